// Round 1
// baseline (499.157 us; speedup 1.0000x reference)
//
#include <hip/hip_runtime.h>
#include <hip/hip_bf16.h>
#include <cstdint>
#include <cstddef>

#define BB 64
#define PP 16384
#define CC 81
#define NOBJ 32

// ---------------- workspace layout (bytes) ----------------
// [0        , 8192   )  prior_for_obj int [B][NO]
// [8192     , 8448   )  n_pos int [B]
// [8448     , 8472   )  acc double[3] = {loc_sum, conf_pos, conf_neg}
// [8704     , 74240  )  part_v float [B][8][NO]
// [74240    , 139776 )  part_i int   [B][8][NO]
// [139776   , 1188352)  lab uint8 [B][P]
// [1188352  , 5382656)  ce_neg float [B][P]

__device__ __forceinline__ float iou_xy(float a0, float a1, float a2, float a3,
                                        float b0, float b1, float b2, float b3) {
    float lx = fmaxf(a0, b0), ly = fmaxf(a1, b1);
    float hx = fminf(a2, b2), hy = fminf(a3, b3);
    float iw = fmaxf(hx - lx, 0.f), ih = fmaxf(hy - ly, 0.f);
    float inter = iw * ih;
    float areaA = (a2 - a0) * (a3 - a1);
    float areaB = (b2 - b0) * (b3 - b1);
    return inter / (areaA + areaB - inter);
}

__global__ void init_kernel(int* n_pos, double* acc) {
    int t = threadIdx.x;
    if (t < BB) n_pos[t] = 0;
    if (t < 3) acc[t] = 0.0;
}

// Stage 1: per (chunk, batch) block computes per-object best prior in its chunk.
__global__ void obj_argmax_stage1(const float* __restrict__ boxes,
                                  const float* __restrict__ priors,
                                  float* __restrict__ part_v,
                                  int* __restrict__ part_i) {
    int chunk = blockIdx.x;  // 0..7
    int b = blockIdx.y;
    int tid = threadIdx.x;
    __shared__ float sB[NOBJ * 4];
    __shared__ float sV[4][NOBJ];
    __shared__ int   sI[4][NOBJ];
    if (tid < NOBJ * 4) sB[tid] = boxes[b * NOBJ * 4 + tid];
    __syncthreads();

    float bv[NOBJ];
    int   bi[NOBJ];
#pragma unroll
    for (int o = 0; o < NOBJ; ++o) { bv[o] = -1.f; bi[o] = 0; }

    int p0 = chunk * (PP / 8);
    for (int i = 0; i < (PP / 8) / 256; ++i) {  // 8 iterations
        int p = p0 + i * 256 + tid;
        float4 pc = ((const float4*)priors)[p];
        float px1 = pc.x - pc.z * 0.5f, py1 = pc.y - pc.w * 0.5f;
        float px2 = pc.x + pc.z * 0.5f, py2 = pc.y + pc.w * 0.5f;
#pragma unroll
        for (int o = 0; o < NOBJ; ++o) {
            float v = iou_xy(sB[o * 4], sB[o * 4 + 1], sB[o * 4 + 2], sB[o * 4 + 3],
                             px1, py1, px2, py2);
            if (v > bv[o]) { bv[o] = v; bi[o] = p; }
        }
    }

    int lane = tid & 63, wid = tid >> 6;
#pragma unroll
    for (int o = 0; o < NOBJ; ++o) {
        float v = bv[o]; int ix = bi[o];
        for (int off = 32; off; off >>= 1) {
            float v2 = __shfl_down(v, off);
            int   i2 = __shfl_down(ix, off);
            if (v2 > v || (v2 == v && i2 < ix)) { v = v2; ix = i2; }
        }
        if (lane == 0) { sV[wid][o] = v; sI[wid][o] = ix; }
    }
    __syncthreads();
    if (tid < NOBJ) {
        float v = sV[0][tid]; int ix = sI[0][tid];
        for (int w = 1; w < 4; ++w) {
            float v2 = sV[w][tid]; int i2 = sI[w][tid];
            if (v2 > v || (v2 == v && i2 < ix)) { v = v2; ix = i2; }
        }
        part_v[(b * 8 + chunk) * NOBJ + tid] = v;
        part_i[(b * 8 + chunk) * NOBJ + tid] = ix;
    }
}

// Stage 2: reduce 8 chunks -> prior_for_obj[b][o]
__global__ void obj_argmax_stage2(const float* __restrict__ part_v,
                                  const int* __restrict__ part_i,
                                  int* __restrict__ pfo) {
    int b = blockIdx.x;
    int o = threadIdx.x;
    if (o < NOBJ) {
        float v = -2.f; int ix = 0;
        for (int c = 0; c < 8; ++c) {
            float v2 = part_v[(b * 8 + c) * NOBJ + o];
            int   i2 = part_i[(b * 8 + c) * NOBJ + o];
            if (v2 > v || (v2 == v && i2 < ix)) { v = v2; ix = i2; }
        }
        pfo[b * NOBJ + o] = ix;
    }
}

// Per-prior matching: label byte + loc-L1 partial sums + n_pos counts.
__global__ void match_kernel(const float* __restrict__ predicted_locs,
                             const float* __restrict__ boxes,
                             const int* __restrict__ labels,
                             const float* __restrict__ priors,
                             const int* __restrict__ pfo,
                             unsigned char* __restrict__ lab_out,
                             int* __restrict__ n_pos,
                             double* __restrict__ loc_acc) {
    int b = blockIdx.y;
    int tid = threadIdx.x;
    int p = blockIdx.x * 256 + tid;
    __shared__ float sB[NOBJ * 4];
    __shared__ int sL[NOBJ];
    __shared__ int sP[NOBJ];
    __shared__ float sLs[4];
    __shared__ int sCs[4];
    if (tid < NOBJ * 4) sB[tid] = boxes[b * NOBJ * 4 + tid];
    if (tid < NOBJ) { sL[tid] = labels[b * NOBJ + tid]; sP[tid] = pfo[b * NOBJ + tid]; }
    __syncthreads();

    float4 pc = ((const float4*)priors)[p];
    float px1 = pc.x - pc.z * 0.5f, py1 = pc.y - pc.w * 0.5f;
    float px2 = pc.x + pc.z * 0.5f, py2 = pc.y + pc.w * 0.5f;

    float bestv = -1.f; int besto = 0;
#pragma unroll
    for (int o = 0; o < NOBJ; ++o) {
        float v = iou_xy(sB[o * 4], sB[o * 4 + 1], sB[o * 4 + 2], sB[o * 4 + 3],
                         px1, py1, px2, py2);
        if (v > bestv) { bestv = v; besto = o; }
    }
    // force-assignment override: last object (highest o) wins, like sequential .set
#pragma unroll
    for (int o = NOBJ - 1; o >= 0; --o) {
        if (sP[o] == p) { besto = o; bestv = 1.0f; break; }
    }
    int lab = (bestv < 0.5f) ? 0 : sL[besto];
    lab_out[(size_t)b * PP + p] = (unsigned char)lab;

    float l1 = 0.f;
    bool pos = (lab != 0);
    if (pos) {
        float bx0 = sB[besto * 4], bx1 = sB[besto * 4 + 1];
        float bx2 = sB[besto * 4 + 2], bx3 = sB[besto * 4 + 3];
        float cx = (bx0 + bx2) * 0.5f, cy = (bx1 + bx3) * 0.5f;
        float w = bx2 - bx0, h = bx3 - bx1;
        float g0 = (cx - pc.x) / (pc.z / 10.0f);
        float g1 = (cy - pc.y) / (pc.w / 10.0f);
        float g2 = __logf(w / pc.z) * 5.0f;
        float g3 = __logf(h / pc.w) * 5.0f;
        float4 pl = ((const float4*)predicted_locs)[(size_t)b * PP + p];
        l1 = fabsf(pl.x - g0) + fabsf(pl.y - g1) + fabsf(pl.z - g2) + fabsf(pl.w - g3);
    }

    for (int off = 32; off; off >>= 1) l1 += __shfl_down(l1, off);
    unsigned long long bal = __ballot(pos);
    int lane = tid & 63, wid = tid >> 6;
    if (lane == 0) { sLs[wid] = l1; sCs[wid] = __popcll(bal); }
    __syncthreads();
    if (tid == 0) {
        float L = sLs[0] + sLs[1] + sLs[2] + sLs[3];
        int cnt = sCs[0] + sCs[1] + sCs[2] + sCs[3];
        if (L != 0.f) atomicAdd(loc_acc, (double)L);
        if (cnt) atomicAdd(&n_pos[b], cnt);
    }
}

// Cross-entropy for every (b,p): 4 lanes per prior, 21 classes/lane in registers.
__global__ void ce_kernel(const float* __restrict__ scores,
                          const unsigned char* __restrict__ lab_arr,
                          float* __restrict__ ce_neg,
                          double* __restrict__ conf_pos_acc) {
    const int total = BB * PP;  // 1048576, divisible by 16
    int tlane = threadIdx.x & 63;
    int g = tlane >> 2;   // group 0..15 within wave
    int r = tlane & 3;    // lane within group
    int wid_global = (blockIdx.x * blockDim.x + threadIdx.x) >> 6;
    int nwaves = (gridDim.x * blockDim.x) >> 6;

    double accpos = 0.0;
    for (int base = wid_global * 16; base < total; base += nwaves * 16) {
        int idx = base + g;
        const float* s = scores + (size_t)idx * CC;
        float v[21];
#pragma unroll
        for (int k = 0; k < 21; ++k) {
            int c = r + 4 * k;
            v[k] = (c < CC) ? s[c] : -3.0e38f;
        }
        float m = v[0];
#pragma unroll
        for (int k = 1; k < 21; ++k) m = fmaxf(m, v[k]);
        m = fmaxf(m, __shfl_xor(m, 1));
        m = fmaxf(m, __shfl_xor(m, 2));
        float e = 0.f;
#pragma unroll
        for (int k = 0; k < 21; ++k) {
            int c = r + 4 * k;
            if (c < CC) e += __expf(v[k] - m);
        }
        e += __shfl_xor(e, 1);
        e += __shfl_xor(e, 2);
        int lab = lab_arr[idx];
        float sl = s[lab];                 // L1-hot reload of the label logit
        float ce = m + __logf(e) - sl;
        if (r == 0) {
            ce_neg[idx] = (lab != 0) ? 0.f : ce;
            if (lab != 0) accpos += (double)ce;
        }
    }
    for (int off = 32; off; off >>= 1) accpos += __shfl_down(accpos, off);
    if (tlane == 0 && accpos != 0.0) atomicAdd(conf_pos_acc, accpos);
}

// Top-K sum of ce_neg per batch row via bit-pattern binary search (K = min(3*n_pos, P)).
__global__ void mine_kernel(const float* __restrict__ ce_neg,
                            const int* __restrict__ n_pos,
                            double* __restrict__ conf_neg_acc) {
    int b = blockIdx.x;
    int tid = threadIdx.x;
    const float* row = ce_neg + (size_t)b * PP;
    float vals[64];
#pragma unroll
    for (int i = 0; i < 64; ++i) vals[i] = row[tid + i * 256];

    int K = 3 * n_pos[b];
    if (K > PP) K = PP;
    __shared__ int sC[4];
    __shared__ float sS[4];
    int lane = tid & 63, wid = tid >> 6;
    if (K <= 0) return;  // uniform

    unsigned lo = 0u, hi = 0xFFFFFFFFu;
    while (lo < hi) {  // <=32 iterations, uniform control flow
        unsigned mid = (unsigned)(((unsigned long long)lo + (unsigned long long)hi + 1ull) >> 1);
        int c = 0;
#pragma unroll
        for (int i = 0; i < 64; ++i) c += (__float_as_uint(vals[i]) >= mid) ? 1 : 0;
        for (int off = 32; off; off >>= 1) c += __shfl_down(c, off);
        if (lane == 0) sC[wid] = c;
        __syncthreads();
        int ctot = sC[0] + sC[1] + sC[2] + sC[3];
        __syncthreads();
        if (ctot >= K) lo = mid; else hi = mid - 1;
    }
    // lo = bit pattern of the K-th largest value x. S = sum(v > x) + (K - count(v > x)) * x.
    float x = __uint_as_float(lo);
    int cgt = 0; float sgt = 0.f;
#pragma unroll
    for (int i = 0; i < 64; ++i) {
        if (__float_as_uint(vals[i]) > lo) { cgt++; sgt += vals[i]; }
    }
    for (int off = 32; off; off >>= 1) {
        cgt += __shfl_down(cgt, off);
        sgt += __shfl_down(sgt, off);
    }
    if (lane == 0) { sC[wid] = cgt; sS[wid] = sgt; }
    __syncthreads();
    if (tid == 0) {
        int cg = sC[0] + sC[1] + sC[2] + sC[3];
        double S = (double)(sS[0] + sS[1] + sS[2] + sS[3]) + (double)(K - cg) * (double)x;
        atomicAdd(conf_neg_acc, S);
    }
}

__global__ void final_kernel(const int* __restrict__ n_pos,
                             const double* __restrict__ acc,
                             float* __restrict__ out) {
    if (threadIdx.x == 0 && blockIdx.x == 0) {
        int tot = 0;
        for (int b = 0; b < BB; ++b) tot += n_pos[b];
        double tp = (double)tot;
        double conf = (acc[1] + acc[2]) / tp;
        double locl = acc[0] / (tp * 4.0);
        out[0] = (float)(conf + locl);
    }
}

extern "C" void kernel_launch(void* const* d_in, const int* in_sizes, int n_in,
                              void* d_out, int out_size, void* d_ws, size_t ws_size,
                              hipStream_t stream) {
    const float* predicted_locs = (const float*)d_in[0];
    const float* scores         = (const float*)d_in[1];
    const float* boxes          = (const float*)d_in[2];
    const int*   labels         = (const int*)d_in[3];
    const float* priors         = (const float*)d_in[4];
    float* out = (float*)d_out;

    char* ws = (char*)d_ws;
    int*    pfo    = (int*)(ws + 0);
    int*    n_pos  = (int*)(ws + 8192);
    double* acc    = (double*)(ws + 8448);
    float*  part_v = (float*)(ws + 8704);
    int*    part_i = (int*)(ws + 74240);
    unsigned char* lab = (unsigned char*)(ws + 139776);
    float*  ce_neg = (float*)(ws + 1188352);

    hipLaunchKernelGGL(init_kernel, dim3(1), dim3(64), 0, stream, n_pos, acc);
    hipLaunchKernelGGL(obj_argmax_stage1, dim3(8, BB), dim3(256), 0, stream,
                       boxes, priors, part_v, part_i);
    hipLaunchKernelGGL(obj_argmax_stage2, dim3(BB), dim3(32), 0, stream,
                       part_v, part_i, pfo);
    hipLaunchKernelGGL(match_kernel, dim3(PP / 256, BB), dim3(256), 0, stream,
                       predicted_locs, boxes, labels, priors, pfo, lab, n_pos, &acc[0]);
    hipLaunchKernelGGL(ce_kernel, dim3(2048), dim3(256), 0, stream,
                       scores, lab, ce_neg, &acc[1]);
    hipLaunchKernelGGL(mine_kernel, dim3(BB), dim3(256), 0, stream,
                       ce_neg, n_pos, &acc[2]);
    hipLaunchKernelGGL(final_kernel, dim3(1), dim3(64), 0, stream, n_pos, acc, out);
}

// Round 2
// 273.485 us; speedup vs baseline: 1.8252x; 1.8252x over previous
//
#include <hip/hip_runtime.h>
#include <hip/hip_bf16.h>
#include <cstdint>
#include <cstddef>

#define BB 64
#define PP 16384
#define CC 81
#define NOBJ 32

// ---------------- workspace layout (bytes) ----------------
// [0       , 8192   )  prior_for_obj int [B][NO]
// [8192    , 8448   )  n_pos int [B]
// [8448    , 8472   )  acc double[3] = {loc_sum, conf_pos, conf_neg}
// [8704    , 1057280)  lab uint8 [B][P]
// [1057280 , 5251584)  ce_neg float [B][P]

__global__ __launch_bounds__(64) void init_kernel(int* n_pos, double* acc) {
    int t = threadIdx.x;
    if (t < BB) n_pos[t] = 0;
    if (t < 3) acc[t] = 0.0;
}

// One block per (object, batch): each thread keeps ONE running argmax -> no spill.
__global__ __launch_bounds__(256) void obj_argmax_kernel(
        const float* __restrict__ boxes,
        const float* __restrict__ priors,
        int* __restrict__ pfo) {
    int o = blockIdx.x;   // 0..NOBJ-1
    int b = blockIdx.y;   // 0..BB-1
    int tid = threadIdx.x;

    float4 bx = ((const float4*)boxes)[b * NOBJ + o];
    float a0 = bx.x, a1 = bx.y, a2 = bx.z, a3 = bx.w;
    float areaA = (a2 - a0) * (a3 - a1);

    float bestv = -1.f;
    int besti = 0;
    for (int i = 0; i < PP / 256; ++i) {   // 64 iterations
        int p = i * 256 + tid;
        float4 pc = ((const float4*)priors)[p];
        float px1 = pc.x - pc.z * 0.5f, py1 = pc.y - pc.w * 0.5f;
        float px2 = pc.x + pc.z * 0.5f, py2 = pc.y + pc.w * 0.5f;
        float lx = fmaxf(a0, px1), ly = fmaxf(a1, py1);
        float hx = fminf(a2, px2), hy = fminf(a3, py2);
        float iw = fmaxf(hx - lx, 0.f), ih = fmaxf(hy - ly, 0.f);
        float inter = iw * ih;
        float areaB = (px2 - px1) * (py2 - py1);
        float v = inter / (areaA + areaB - inter);
        if (v > bestv) { bestv = v; besti = p; }   // p increasing -> first occurrence
    }
    // wave reduce (argmax, smaller index wins ties)
    for (int off = 32; off; off >>= 1) {
        float v2 = __shfl_down(bestv, off);
        int   i2 = __shfl_down(besti, off);
        if (v2 > bestv || (v2 == bestv && i2 < besti)) { bestv = v2; besti = i2; }
    }
    __shared__ float sV[4];
    __shared__ int   sI[4];
    int lane = tid & 63, wid = tid >> 6;
    if (lane == 0) { sV[wid] = bestv; sI[wid] = besti; }
    __syncthreads();
    if (tid == 0) {
        float v = sV[0]; int ix = sI[0];
        for (int w = 1; w < 4; ++w) {
            if (sV[w] > v || (sV[w] == v && sI[w] < ix)) { v = sV[w]; ix = sI[w]; }
        }
        pfo[b * NOBJ + o] = ix;
    }
}

// Per-prior matching: label byte + loc-L1 partial sums + n_pos counts.
__global__ __launch_bounds__(256) void match_kernel(
                             const float* __restrict__ predicted_locs,
                             const float* __restrict__ boxes,
                             const int* __restrict__ labels,
                             const float* __restrict__ priors,
                             const int* __restrict__ pfo,
                             unsigned char* __restrict__ lab_out,
                             int* __restrict__ n_pos,
                             double* __restrict__ loc_acc) {
    int b = blockIdx.y;
    int tid = threadIdx.x;
    int p = blockIdx.x * 256 + tid;
    __shared__ float sB[NOBJ * 4];
    __shared__ int sL[NOBJ];
    __shared__ int sP[NOBJ];
    __shared__ float sLs[4];
    __shared__ int sCs[4];
    if (tid < NOBJ * 4) sB[tid] = boxes[b * NOBJ * 4 + tid];
    if (tid < NOBJ) { sL[tid] = labels[b * NOBJ + tid]; sP[tid] = pfo[b * NOBJ + tid]; }
    __syncthreads();

    float4 pc = ((const float4*)priors)[p];
    float px1 = pc.x - pc.z * 0.5f, py1 = pc.y - pc.w * 0.5f;
    float px2 = pc.x + pc.z * 0.5f, py2 = pc.y + pc.w * 0.5f;

    float bestv = -1.f; int besto = 0;
#pragma unroll
    for (int o = 0; o < NOBJ; ++o) {
        float lx = fmaxf(sB[o * 4], px1), ly = fmaxf(sB[o * 4 + 1], py1);
        float hx = fminf(sB[o * 4 + 2], px2), hy = fminf(sB[o * 4 + 3], py2);
        float iw = fmaxf(hx - lx, 0.f), ih = fmaxf(hy - ly, 0.f);
        float inter = iw * ih;
        float areaA = (sB[o * 4 + 2] - sB[o * 4]) * (sB[o * 4 + 3] - sB[o * 4 + 1]);
        float areaB = (px2 - px1) * (py2 - py1);
        float v = inter / (areaA + areaB - inter);
        if (v > bestv) { bestv = v; besto = o; }
    }
    // force-assignment override: last object (highest o) wins, like sequential scatter
#pragma unroll
    for (int o = NOBJ - 1; o >= 0; --o) {
        if (sP[o] == p) { besto = o; bestv = 1.0f; break; }
    }
    int lab = (bestv < 0.5f) ? 0 : sL[besto];
    lab_out[(size_t)b * PP + p] = (unsigned char)lab;

    float l1 = 0.f;
    bool pos = (lab != 0);
    if (pos) {
        float bx0 = sB[besto * 4], bx1 = sB[besto * 4 + 1];
        float bx2 = sB[besto * 4 + 2], bx3 = sB[besto * 4 + 3];
        float cx = (bx0 + bx2) * 0.5f, cy = (bx1 + bx3) * 0.5f;
        float w = bx2 - bx0, h = bx3 - bx1;
        float g0 = (cx - pc.x) / (pc.z / 10.0f);
        float g1 = (cy - pc.y) / (pc.w / 10.0f);
        float g2 = __logf(w / pc.z) * 5.0f;
        float g3 = __logf(h / pc.w) * 5.0f;
        float4 pl = ((const float4*)predicted_locs)[(size_t)b * PP + p];
        l1 = fabsf(pl.x - g0) + fabsf(pl.y - g1) + fabsf(pl.z - g2) + fabsf(pl.w - g3);
    }

    for (int off = 32; off; off >>= 1) l1 += __shfl_down(l1, off);
    unsigned long long bal = __ballot(pos);
    int lane = tid & 63, wid = tid >> 6;
    if (lane == 0) { sLs[wid] = l1; sCs[wid] = __popcll(bal); }
    __syncthreads();
    if (tid == 0) {
        float L = sLs[0] + sLs[1] + sLs[2] + sLs[3];
        int cnt = sCs[0] + sCs[1] + sCs[2] + sCs[3];
        if (L != 0.f) atomicAdd(loc_acc, (double)L);
        if (cnt) atomicAdd(&n_pos[b], cnt);
    }
}

// Cross-entropy: each wave stages 16 rows (5184B, 16B-aligned) into its own LDS
// region via coalesced float4, then 4 lanes per row compute logsumexp from LDS.
__global__ __launch_bounds__(256) void ce_kernel(
                          const float* __restrict__ scores,
                          const unsigned char* __restrict__ lab_arr,
                          float* __restrict__ ce_neg,
                          double* __restrict__ conf_pos_acc) {
    __shared__ float lds[4][16 * CC];   // 4 waves x 1296 floats = 20736 B
    const int total_tiles = (BB * PP) / 16;  // 65536
    int tid = threadIdx.x;
    int lane = tid & 63;
    int wv = tid >> 6;
    int g = lane >> 2, r = lane & 3;
    int wgl = blockIdx.x * 4 + wv;
    int nw = gridDim.x * 4;
    float* L = lds[wv];

    double accpos = 0.0;
    for (int t = wgl; t < total_tiles; t += nw) {
        size_t row0 = (size_t)t * 16;
        const float4* src = (const float4*)(scores + row0 * CC);  // 324 float4, aligned
        float4* dst = (float4*)L;
#pragma unroll
        for (int k = 0; k < 5; ++k) dst[lane + 64 * k] = src[lane + 64 * k];
        if (lane < 4) dst[320 + lane] = src[320 + lane];
        // wave-internal LDS producer->consumer; compiler inserts lgkmcnt waits

        const float* row = L + g * CC;
        float v[21];
#pragma unroll
        for (int k = 0; k < 21; ++k) {
            int c = r + 4 * k;
            v[k] = (c < CC) ? row[c] : -3.0e38f;
        }
        float m = v[0];
#pragma unroll
        for (int k = 1; k < 21; ++k) m = fmaxf(m, v[k]);
        m = fmaxf(m, __shfl_xor(m, 1));
        m = fmaxf(m, __shfl_xor(m, 2));
        float e = 0.f;
#pragma unroll
        for (int k = 0; k < 21; ++k) {
            int c = r + 4 * k;
            if (c < CC) e += __expf(v[k] - m);
        }
        e += __shfl_xor(e, 1);
        e += __shfl_xor(e, 2);

        int idx = (int)row0 + g;
        int lab = lab_arr[idx];
        float sl = row[lab];
        float ce = m + __logf(e) - sl;
        if (r == 0) {
            ce_neg[idx] = (lab != 0) ? 0.f : ce;
            if (lab != 0) accpos += (double)ce;
        }
    }
    for (int off = 32; off; off >>= 1) accpos += __shfl_down(accpos, off);
    if (lane == 0 && accpos != 0.0) atomicAdd(conf_pos_acc, accpos);
}

// Top-K sum of ce_neg per batch row via bit-pattern binary search (K = min(3*n_pos, P)).
__global__ __launch_bounds__(256, 1) void mine_kernel(
                            const float* __restrict__ ce_neg,
                            const int* __restrict__ n_pos,
                            double* __restrict__ conf_neg_acc) {
    int b = blockIdx.x;
    int tid = threadIdx.x;
    const float* row = ce_neg + (size_t)b * PP;
    float vals[64];
#pragma unroll
    for (int i = 0; i < 64; ++i) vals[i] = row[tid + i * 256];

    int K = 3 * n_pos[b];
    if (K > PP) K = PP;
    __shared__ int sC[4];
    __shared__ float sS[4];
    int lane = tid & 63, wid = tid >> 6;
    if (K <= 0) return;  // uniform across block

    unsigned lo = 0u, hi = 0xFFFFFFFFu;
    while (lo < hi) {  // <=32 iterations, uniform control flow
        unsigned mid = (unsigned)(((unsigned long long)lo + (unsigned long long)hi + 1ull) >> 1);
        int c = 0;
#pragma unroll
        for (int i = 0; i < 64; ++i) c += (__float_as_uint(vals[i]) >= mid) ? 1 : 0;
        for (int off = 32; off; off >>= 1) c += __shfl_down(c, off);
        if (lane == 0) sC[wid] = c;
        __syncthreads();
        int ctot = sC[0] + sC[1] + sC[2] + sC[3];
        __syncthreads();
        if (ctot >= K) lo = mid; else hi = mid - 1;
    }
    // lo = bit pattern of K-th largest value x. S = sum(v > x) + (K - count(v > x)) * x.
    float x = __uint_as_float(lo);
    int cgt = 0; float sgt = 0.f;
#pragma unroll
    for (int i = 0; i < 64; ++i) {
        if (__float_as_uint(vals[i]) > lo) { cgt++; sgt += vals[i]; }
    }
    for (int off = 32; off; off >>= 1) {
        cgt += __shfl_down(cgt, off);
        sgt += __shfl_down(sgt, off);
    }
    if (lane == 0) { sC[wid] = cgt; sS[wid] = sgt; }
    __syncthreads();
    if (tid == 0) {
        int cg = sC[0] + sC[1] + sC[2] + sC[3];
        double S = (double)(sS[0] + sS[1] + sS[2] + sS[3]) + (double)(K - cg) * (double)x;
        atomicAdd(conf_neg_acc, S);
    }
}

__global__ __launch_bounds__(64) void final_kernel(
                             const int* __restrict__ n_pos,
                             const double* __restrict__ acc,
                             float* __restrict__ out) {
    if (threadIdx.x == 0 && blockIdx.x == 0) {
        int tot = 0;
        for (int b = 0; b < BB; ++b) tot += n_pos[b];
        double tp = (double)tot;
        double conf = (acc[1] + acc[2]) / tp;
        double locl = acc[0] / (tp * 4.0);
        out[0] = (float)(conf + locl);
    }
}

extern "C" void kernel_launch(void* const* d_in, const int* in_sizes, int n_in,
                              void* d_out, int out_size, void* d_ws, size_t ws_size,
                              hipStream_t stream) {
    const float* predicted_locs = (const float*)d_in[0];
    const float* scores         = (const float*)d_in[1];
    const float* boxes          = (const float*)d_in[2];
    const int*   labels         = (const int*)d_in[3];
    const float* priors         = (const float*)d_in[4];
    float* out = (float*)d_out;

    char* ws = (char*)d_ws;
    int*    pfo    = (int*)(ws + 0);
    int*    n_pos  = (int*)(ws + 8192);
    double* acc    = (double*)(ws + 8448);
    unsigned char* lab = (unsigned char*)(ws + 8704);
    float*  ce_neg = (float*)(ws + 1057280);

    hipLaunchKernelGGL(init_kernel, dim3(1), dim3(64), 0, stream, n_pos, acc);
    hipLaunchKernelGGL(obj_argmax_kernel, dim3(NOBJ, BB), dim3(256), 0, stream,
                       boxes, priors, pfo);
    hipLaunchKernelGGL(match_kernel, dim3(PP / 256, BB), dim3(256), 0, stream,
                       predicted_locs, boxes, labels, priors, pfo, lab, n_pos, &acc[0]);
    hipLaunchKernelGGL(ce_kernel, dim3(2048), dim3(256), 0, stream,
                       scores, lab, ce_neg, &acc[1]);
    hipLaunchKernelGGL(mine_kernel, dim3(BB), dim3(256), 0, stream,
                       ce_neg, n_pos, &acc[2]);
    hipLaunchKernelGGL(final_kernel, dim3(1), dim3(64), 0, stream, n_pos, acc, out);
}